// Round 7
// baseline (444.555 us; speedup 1.0000x reference)
//
#include <hip/hip_runtime.h>

#define NN 100000
#define DD 128
#define EE 1600000
#define BN_EPS 1e-5f
#define NBLK 3125   // NN/32 gemm blocks

using bf16x8 = __attribute__((ext_vector_type(8))) short;
using f32x4  = __attribute__((ext_vector_type(4))) float;
using u16x8  = __attribute__((ext_vector_type(8))) unsigned short;

__device__ __forceinline__ unsigned short bf16r(float f) {
    unsigned u = __float_as_uint(f);
    u += 0x7FFF + ((u >> 16) & 1);   // round-to-nearest-even
    return (unsigned short)(u >> 16);
}
__device__ __forceinline__ float bf2f(unsigned short h) {
    return __uint_as_float((unsigned)h << 16);
}

// ---------------- degree histogram + per-edge rank, XCD-private L2 atomics ----------------
// pack[xcd][node]: lo16 = outdeg count, hi16 = indeg count. Workgroup-scope atomics
// execute at the issuing XCD's L2 (no fabric round-trip); copy k is only touched by
// blocks physically on XCD k (s_getreg HW_REG_XCC_ID), so L2-level atomicity suffices.
// dst atomic return = XCD-local rank -> rank4 = local_rank | (xcd<<16).
__global__ void deg4_kernel(const int4* __restrict__ src4, const int4* __restrict__ dst4,
                            unsigned* __restrict__ pack, int4* __restrict__ rank4) {
    unsigned xcc;
    asm("s_getreg_b32 %0, hwreg(HW_REG_XCC_ID)" : "=s"(xcc));
    xcc &= 7;
    unsigned* mp = pack + (size_t)xcc * NN;
    const unsigned tag = xcc << 16;
    int i = blockIdx.x * blockDim.x + threadIdx.x;
    if (i < EE / 4) {
        int4 s = src4[i];
        int4 d = dst4[i];
        __hip_atomic_fetch_add(&mp[s.x], 1u, __ATOMIC_RELAXED, __HIP_MEMORY_SCOPE_WORKGROUP);
        __hip_atomic_fetch_add(&mp[s.y], 1u, __ATOMIC_RELAXED, __HIP_MEMORY_SCOPE_WORKGROUP);
        __hip_atomic_fetch_add(&mp[s.z], 1u, __ATOMIC_RELAXED, __HIP_MEMORY_SCOPE_WORKGROUP);
        __hip_atomic_fetch_add(&mp[s.w], 1u, __ATOMIC_RELAXED, __HIP_MEMORY_SCOPE_WORKGROUP);
        unsigned o0 = __hip_atomic_fetch_add(&mp[d.x], 0x10000u, __ATOMIC_RELAXED, __HIP_MEMORY_SCOPE_WORKGROUP);
        unsigned o1 = __hip_atomic_fetch_add(&mp[d.y], 0x10000u, __ATOMIC_RELAXED, __HIP_MEMORY_SCOPE_WORKGROUP);
        unsigned o2 = __hip_atomic_fetch_add(&mp[d.z], 0x10000u, __ATOMIC_RELAXED, __HIP_MEMORY_SCOPE_WORKGROUP);
        unsigned o3 = __hip_atomic_fetch_add(&mp[d.w], 0x10000u, __ATOMIC_RELAXED, __HIP_MEMORY_SCOPE_WORKGROUP);
        int4 r;
        r.x = (int)((o0 >> 16) | tag);
        r.y = (int)((o1 >> 16) | tag);
        r.z = (int)((o2 >> 16) | tag);
        r.w = (int)((o3 >> 16) | tag);
        rank4[i] = r;
    }
}

// ---------------- merge the 8 XCD copies: indeg, ns, nd, per-XCD exclusive base ----------------
__global__ void merge_kernel(const unsigned* __restrict__ pack,
                             int* __restrict__ indeg, float* __restrict__ ns,
                             float* __restrict__ nd, unsigned short* __restrict__ base16) {
    int n = blockIdx.x * blockDim.x + threadIdx.x;
    if (n < NN) {
        int od = 0;
        int pre = 0;
        u16x8 bb;
#pragma unroll
        for (int k = 0; k < 8; ++k) {
            unsigned v = pack[(size_t)k * NN + n];
            bb[k] = (unsigned short)pre;      // exclusive prefix of indeg counts
            od += (int)(v & 0xFFFFu);
            pre += (int)(v >> 16);
        }
        indeg[n] = pre;
        ns[n] = rsqrtf(fmaxf((float)od, 1.0f));
        nd[n] = rsqrtf(fmaxf((float)pre, 1.0f));
        ((u16x8*)base16)[n] = bb;
    }
}

// ---------------- scan phase 1: per-block inclusive scan of indeg ----------------
__global__ __launch_bounds__(1024) void scan1_kernel(const int* __restrict__ indeg,
                                                     int* __restrict__ partial,
                                                     int* __restrict__ blocksum) {
    __shared__ int s[1024];
    int t = threadIdx.x;
    int idx = blockIdx.x * 1024 + t;
    int v = (idx < NN) ? indeg[idx] : 0;
    s[t] = v;
    __syncthreads();
    for (int off = 1; off < 1024; off <<= 1) {
        int x = (t >= off) ? s[t - off] : 0;
        __syncthreads();
        s[t] += x;
        __syncthreads();
    }
    if (idx < NN) partial[idx] = s[t] - v;  // exclusive within block
    if (t == 1023) blocksum[blockIdx.x] = s[t];
}

// ---------------- scan 2+3: row_ofs + per-XCD row_ofs2 (row_ofs2 aliases pack) ----------------
__global__ void scan23_kernel(const int* __restrict__ partial, const int* __restrict__ blocksum,
                              const unsigned short* __restrict__ base16,
                              int* __restrict__ row_ofs, int* __restrict__ row_ofs2) {
    __shared__ int s[128];
    int t = threadIdx.x;
    if (t < 128) s[t] = (t < 98) ? blocksum[t] : 0;
    __syncthreads();
    for (int off = 1; off < 128; off <<= 1) {
        int x = (t < 128 && t >= off) ? s[t - off] : 0;
        __syncthreads();
        if (t < 128) s[t] += x;
        __syncthreads();
    }
    int i = blockIdx.x * blockDim.x + t;
    if (i < NN) {
        int bk = i >> 10;
        int ro = partial[i] + s[bk] - blocksum[bk];  // + exclusive block offset
        row_ofs[i] = ro;
        u16x8 bb = ((const u16x8*)base16)[i];
#pragma unroll
        for (int k = 0; k < 8; ++k) row_ofs2[(size_t)i * 8 + k] = ro + (int)bb[k];
        if (i == 0) row_ofs[NN] = EE;
    }
}

// ---------------- feats -> bf16 pre-scaled by ns ----------------
__global__ void cvt_kernel(const float4* __restrict__ feats4, const float* __restrict__ ns,
                           ushort4* __restrict__ fb4) {
    int i = blockIdx.x * blockDim.x + threadIdx.x;  // NN*32 = 3.2M
    if (i < NN * 32) {
        float s = ns[i >> 5];
        float4 v = feats4[i];
        ushort4 h;
        h.x = bf16r(v.x * s);
        h.y = bf16r(v.y * s);
        h.z = bf16r(v.z * s);
        h.w = bf16r(v.w * s);
        fb4[i] = h;
    }
}

// ---------------- CSR fill, atomic-free: slot = row_ofs2[dst][xcd] + local_rank ----------------
__global__ void fill4_kernel(const int4* __restrict__ src4, const int4* __restrict__ dst4,
                             const int4* __restrict__ rank4, const int* __restrict__ row_ofs2,
                             int* __restrict__ e_src) {
    int i = blockIdx.x * blockDim.x + threadIdx.x;
    if (i < EE / 4) {
        int4 s = src4[i];
        int4 d = dst4[i];
        int4 p = rank4[i];
        unsigned px = (unsigned)p.x, py = (unsigned)p.y, pz = (unsigned)p.z, pw = (unsigned)p.w;
        e_src[row_ofs2[(size_t)d.x * 8 + (px >> 16)] + (int)(px & 0xFFFFu)] = s.x;
        e_src[row_ofs2[(size_t)d.y * 8 + (py >> 16)] + (int)(py & 0xFFFFu)] = s.y;
        e_src[row_ofs2[(size_t)d.z * 8 + (pz >> 16)] + (int)(pz & 0xFFFFu)] = s.z;
        e_src[row_ofs2[(size_t)d.w * 8 + (pw >> 16)] + (int)(pw & 0xFFFFu)] = s.w;
    }
}

// ---------------- weight pre-pack into MFMA B-fragment order, bf16 hi/lo ----------------
// layout: wb[(g*2+p)*32 + ct*4 + ks][lane 0..63][i 0..7] bf16, fragment = 1KB contiguous
// B-frag for mfma_f32_16x16x32_bf16: lane l, elem i -> B[k = ks*32 + (l>>4)*8 + i][col = ct*16 + (l&15)]
__global__ void prepw_kernel(const float* __restrict__ W, const float* __restrict__ Wr,
                             unsigned short* __restrict__ wb) {
    int g = blockIdx.x >> 5;          // 0 = W, 1 = Wr
    int f = blockIdx.x & 31;          // ct*4 + ks
    int ct = f >> 2, ks = f & 3;
    int l = threadIdx.x;              // 0..63
    const float* G = g ? Wr : W;
    unsigned short* hi = wb + (((size_t)(g * 2 + 0) * 32 + f) * 64 + l) * 8;
    unsigned short* lo = wb + (((size_t)(g * 2 + 1) * 32 + f) * 64 + l) * 8;
    for (int i = 0; i < 8; ++i) {
        int k = ks * 32 + (l >> 4) * 8 + i;
        int col = ct * 16 + (l & 15);
        float w = G[k * 128 + col];
        unsigned uh = __float_as_uint(w) & 0xFFFF0000u;  // truncated hi part
        hi[i] = (unsigned short)(uh >> 16);
        lo[i] = bf16r(w - __uint_as_float(uh));          // residual -> lo
    }
}

// ---------------- gather-aggregate: latency-bound, no LDS, max occupancy ----------------
__device__ __forceinline__ void accum8(float* a, int4 u) {
    a[0] += __uint_as_float((unsigned)u.x << 16);
    a[1] += __uint_as_float((unsigned)u.x & 0xFFFF0000u);
    a[2] += __uint_as_float((unsigned)u.y << 16);
    a[3] += __uint_as_float((unsigned)u.y & 0xFFFF0000u);
    a[4] += __uint_as_float((unsigned)u.z << 16);
    a[5] += __uint_as_float((unsigned)u.z & 0xFFFF0000u);
    a[6] += __uint_as_float((unsigned)u.w << 16);
    a[7] += __uint_as_float((unsigned)u.w & 0xFFFF0000u);
}

__global__ __launch_bounds__(256, 6) void gather_kernel(
    const int4* __restrict__ fbi, const float* __restrict__ nd,
    const int* __restrict__ row_ofs, const int* __restrict__ e_src,
    float* __restrict__ y) {
    const int lane = threadIdx.x & 15;
    const int grp = threadIdx.x >> 4;                 // 0..15
    const int node = blockIdx.x * 16 + grp;           // 6250*16 = 100000 exact
    const int beg = row_ofs[node];
    const int end = row_ofs[node + 1];

    float a0[8] = {0.f, 0.f, 0.f, 0.f, 0.f, 0.f, 0.f, 0.f};
    float a1[8] = {0.f, 0.f, 0.f, 0.f, 0.f, 0.f, 0.f, 0.f};

    for (int e = beg; e < end; e += 16) {
        int cnt = end - e;
        if (cnt > 16) cnt = 16;
        int myidx = (lane < cnt) ? e_src[e + lane] : 0;
        int j = 0;
        for (; j + 3 < cnt; j += 4) {
            int s0 = __shfl(myidx, j, 16);
            int s1 = __shfl(myidx, j + 1, 16);
            int s2 = __shfl(myidx, j + 2, 16);
            int s3 = __shfl(myidx, j + 3, 16);
            int4 u0 = fbi[(size_t)s0 * 16 + lane];
            int4 u1 = fbi[(size_t)s1 * 16 + lane];
            int4 u2 = fbi[(size_t)s2 * 16 + lane];
            int4 u3 = fbi[(size_t)s3 * 16 + lane];
            accum8(a0, u0);
            accum8(a1, u1);
            accum8(a0, u2);
            accum8(a1, u3);
        }
        for (; j < cnt; ++j) {
            int s0 = __shfl(myidx, j, 16);
            int4 u0 = fbi[(size_t)s0 * 16 + lane];
            accum8(a0, u0);
        }
    }

    float snd = nd[node];
    float4 o0, o1;
    o0.x = (a0[0] + a1[0]) * snd;
    o0.y = (a0[1] + a1[1]) * snd;
    o0.z = (a0[2] + a1[2]) * snd;
    o0.w = (a0[3] + a1[3]) * snd;
    o1.x = (a0[4] + a1[4]) * snd;
    o1.y = (a0[5] + a1[5]) * snd;
    o1.z = (a0[6] + a1[6]) * snd;
    o1.w = (a0[7] + a1[7]) * snd;
    ((float4*)y)[(size_t)node * 32 + lane * 2] = o0;
    ((float4*)y)[(size_t)node * 32 + lane * 2 + 1] = o1;
}

// ---------------- dual MFMA GEMM + bias/relu/add + per-block BN partials ----------------
__device__ __forceinline__ void hilo4(float4 v, ushort4& h, ushort4& l) {
    unsigned u0 = __float_as_uint(v.x) & 0xFFFF0000u;
    unsigned u1 = __float_as_uint(v.y) & 0xFFFF0000u;
    unsigned u2 = __float_as_uint(v.z) & 0xFFFF0000u;
    unsigned u3 = __float_as_uint(v.w) & 0xFFFF0000u;
    h.x = (unsigned short)(u0 >> 16);
    h.y = (unsigned short)(u1 >> 16);
    h.z = (unsigned short)(u2 >> 16);
    h.w = (unsigned short)(u3 >> 16);
    l.x = bf16r(v.x - __uint_as_float(u0));
    l.y = bf16r(v.y - __uint_as_float(u1));
    l.z = bf16r(v.z - __uint_as_float(u2));
    l.w = bf16r(v.w - __uint_as_float(u3));
}

__global__ __launch_bounds__(256, 4) void gemm_kernel(
    const float4* __restrict__ feats4,
    const unsigned short* __restrict__ wb,
    const float* __restrict__ b, const float* __restrict__ br,
    float* y, float* __restrict__ part_sum, float* __restrict__ part_sq) {
    __shared__ unsigned short AsH[32 * 128];
    __shared__ unsigned short AsL[32 * 128];
    __shared__ unsigned short FsH[32 * 128];
    __shared__ unsigned short FsL[32 * 128];

    const int tid = threadIdx.x;
    const int block_row = blockIdx.x * 32;
    const float4* agg4 = (const float4*)y;   // NOT restrict: aliases the y store

    // ---- coalesced staging: agg (from y) + feats -> bf16 hi/lo, swizzled LDS ----
    for (int i = tid; i < 1024; i += 256) {
        int r = i >> 5;
        int c4 = i & 31;
        size_t g = (size_t)(block_row + r) * 32 + c4;
        float4 a = agg4[g];
        float4 f = feats4[g];
        int off = (r * 256 + ((c4 * 8) ^ ((r & 7) << 4))) >> 1;  // ushort index
        ushort4 h, l;
        hilo4(a, h, l);
        *(ushort4*)(&AsH[off]) = h;
        *(ushort4*)(&AsL[off]) = l;
        hilo4(f, h, l);
        *(ushort4*)(&FsH[off]) = h;
        *(ushort4*)(&FsL[off]) = l;
    }
    __syncthreads();

    // ---- MFMA phase: wave w covers all 32 rows x cols [w*32, w*32+31] ----
    const int w = tid >> 6;
    const int l = tid & 63;
    const int lr = l & 15;
    const int lh = l >> 4;
    const int ct0 = w * 2;
    const bf16x8* WB = (const bf16x8*)wb;

    const f32x4 fzero = {0.f, 0.f, 0.f, 0.f};
    f32x4 aC[2][2], aR[2][2];  // [row-frag][col-tile]
#pragma unroll
    for (int r = 0; r < 2; ++r)
#pragma unroll
        for (int c = 0; c < 2; ++c) { aC[r][c] = fzero; aR[r][c] = fzero; }

#pragma unroll 1
    for (int ks = 0; ks < 4; ++ks) {
        bf16x8 ah[2], al[2], fh[2], fl[2];
#pragma unroll
        for (int r = 0; r < 2; ++r) {
            int row = r * 16 + lr;
            int off = (row * 256 + ((ks * 64 + lh * 16) ^ ((row & 7) << 4))) >> 1;
            ah[r] = *(const bf16x8*)(&AsH[off]);
            al[r] = *(const bf16x8*)(&AsL[off]);
            fh[r] = *(const bf16x8*)(&FsH[off]);
            fl[r] = *(const bf16x8*)(&FsL[off]);
        }
#pragma unroll
        for (int c = 0; c < 2; ++c) {
            int fr = (ct0 + c) * 4 + ks;
            bf16x8 wh  = WB[(0 * 32 + fr) * 64 + l];
            bf16x8 wl  = WB[(1 * 32 + fr) * 64 + l];
            bf16x8 wrh = WB[(2 * 32 + fr) * 64 + l];
            bf16x8 wrl = WB[(3 * 32 + fr) * 64 + l];
#pragma unroll
            for (int r = 0; r < 2; ++r) {
                aC[r][c] = __builtin_amdgcn_mfma_f32_16x16x32_bf16(ah[r], wh, aC[r][c], 0, 0, 0);
                aC[r][c] = __builtin_amdgcn_mfma_f32_16x16x32_bf16(al[r], wh, aC[r][c], 0, 0, 0);
                aC[r][c] = __builtin_amdgcn_mfma_f32_16x16x32_bf16(ah[r], wl, aC[r][c], 0, 0, 0);
                aR[r][c] = __builtin_amdgcn_mfma_f32_16x16x32_bf16(fh[r], wrh, aR[r][c], 0, 0, 0);
                aR[r][c] = __builtin_amdgcn_mfma_f32_16x16x32_bf16(fl[r], wrh, aR[r][c], 0, 0, 0);
                aR[r][c] = __builtin_amdgcn_mfma_f32_16x16x32_bf16(fh[r], wrl, aR[r][c], 0, 0, 0);
            }
        }
    }

    // ---- epilogue: bias/relu/add, store, per-block BN partials (no atomics) ----
    // C/D layout: row = (l>>4)*4 + i, col = l&15 within each 16x16 tile
#pragma unroll
    for (int c = 0; c < 2; ++c) {
        int col = (ct0 + c) * 16 + lr;
        float bv = b[col], brv = br[col];
        float cs = 0.f, cq = 0.f;
#pragma unroll
        for (int r = 0; r < 2; ++r) {
#pragma unroll
            for (int i = 0; i < 4; ++i) {
                float o = fmaxf(aC[r][c][i] + bv, 0.f) + fmaxf(aR[r][c][i] + brv, 0.f);
                int grow = block_row + r * 16 + lh * 4 + i;
                y[(size_t)grow * 128 + col] = o;
                cs += o;
                cq += o * o;
            }
        }
        cs += __shfl_xor(cs, 16); cs += __shfl_xor(cs, 32);
        cq += __shfl_xor(cq, 16); cq += __shfl_xor(cq, 32);
        if (lh == 0) {
            part_sum[(size_t)blockIdx.x * 128 + col] = cs;
            part_sq[(size_t)blockIdx.x * 128 + col] = cq;
        }
    }
}

// ---------------- fold the 3125 per-block partials into colsum/colsumsq ----------------
__global__ __launch_bounds__(256) void colreduce_kernel(
    const float* __restrict__ part_sum, const float* __restrict__ part_sq,
    float* __restrict__ colsum, float* __restrict__ colsumsq) {
    int j = blockIdx.x;            // 0..127 (column)
    int t = threadIdx.x;           // 0..255
    float s = 0.f, q = 0.f;
    for (int bb = t; bb < NBLK; bb += 256) {
        s += part_sum[(size_t)bb * 128 + j];
        q += part_sq[(size_t)bb * 128 + j];
    }
#pragma unroll
    for (int off = 1; off < 64; off <<= 1) {
        s += __shfl_xor(s, off);
        q += __shfl_xor(q, off);
    }
    __shared__ float ss[4], qq[4];
    if ((t & 63) == 0) { ss[t >> 6] = s; qq[t >> 6] = q; }
    __syncthreads();
    if (t == 0) {
        colsum[j] = ss[0] + ss[1] + ss[2] + ss[3];
        colsumsq[j] = qq[0] + qq[1] + qq[2] + qq[3];
    }
}

// ---------------- BN stats + apply fused ----------------
__global__ void apply2_kernel(float4* __restrict__ y4,
                              const float* __restrict__ colsum, const float* __restrict__ colsumsq,
                              const float* __restrict__ gamma, const float* __restrict__ beta) {
    __shared__ float sc4[128], sh4[128];
    int t = threadIdx.x;
    if (t < 128) {
        const float inv_n = 1.0f / (float)NN;
        float mean = colsum[t] * inv_n;
        float var = colsumsq[t] * inv_n - mean * mean;
        float s = gamma[t] * rsqrtf(var + BN_EPS);
        sc4[t] = s;
        sh4[t] = beta[t] - mean * s;
    }
    __syncthreads();
    int i = blockIdx.x * 256 + t;
    if (i < NN * 32) {
        int c = (i & 31) * 4;
        float4 v = y4[i];
        v.x = v.x * sc4[c + 0] + sh4[c + 0];
        v.y = v.y * sc4[c + 1] + sh4[c + 1];
        v.z = v.z * sc4[c + 2] + sh4[c + 2];
        v.w = v.w * sc4[c + 3] + sh4[c + 3];
        y4[i] = v;
    }
}

extern "C" void kernel_launch(void* const* d_in, const int* in_sizes, int n_in,
                              void* d_out, int out_size, void* d_ws, size_t ws_size,
                              hipStream_t stream) {
    const float* feats = (const float*)d_in[0];
    const int* src = (const int*)d_in[1];
    const int* dst = (const int*)d_in[2];
    const float* W = (const float*)d_in[3];
    const float* b = (const float*)d_in[4];
    const float* Wr = (const float*)d_in[5];
    const float* br = (const float*)d_in[6];
    const float* gamma = (const float*)d_in[7];
    const float* beta = (const float*)d_in[8];
    float* y = (float*)d_out;

    // workspace carve
    char* ws = (char*)d_ws;
    ushort4* fb4 = (ushort4*)ws;                              // NN*32 ushort4 = 25.6 MB
    unsigned* pack = (unsigned*)(ws + (size_t)NN * 32 * 8);   // 8*NN uints = 3.2 MB
    int* row_ofs2 = (int*)pack;                               // ALIAS: pack dead after merge
    unsigned short* base16 = (unsigned short*)(pack + 8 * (size_t)NN);  // NN*8 u16 = 1.6 MB
    float* ns = (float*)(base16 + 8 * (size_t)NN);            // NN
    float* nd = ns + NN;                                      // NN
    int* row_ofs = (int*)(nd + NN);                           // NN+1
    int* indeg = row_ofs + NN + 1;                            // NN (merged sum)
    int* partial = indeg + NN;                                // NN
    int* blocksum = partial + NN;                             // 98 (pad 128)
    int* e_src = blocksum + 128;                              // EE
    float* colsum = (float*)(e_src + EE);                     // 128
    float* colsumsq = colsum + DD;                            // 128
    // wb: 256B-aligned, 2 gemms x 2 parts x 32 frags x 64 lanes x 8 bf16 = 128 KB
    unsigned long long wbofs = (unsigned long long)((char*)(colsumsq + DD) - ws);
    wbofs = (wbofs + 255ull) & ~255ull;
    unsigned short* wb = (unsigned short*)(ws + wbofs);
    // rank: 16B-aligned, EE ints = 6.4 MB (part_sum/part_sq alias it: rank dead after fill)
    unsigned long long rkofs = wbofs + (unsigned long long)4 * 32 * 64 * 8 * 2;
    rkofs = (rkofs + 255ull) & ~255ull;
    int4* rank4 = (int4*)(ws + rkofs);
    float* part_sum = (float*)rank4;                          // NBLK*128 = 1.6 MB
    float* part_sq = part_sum + (size_t)NBLK * 128;           // 1.6 MB (both fit in 6.4 MB)

    hipMemsetAsync(pack, 0, 8 * (size_t)NN * sizeof(unsigned), stream);

    prepw_kernel<<<64, 64, 0, stream>>>(W, Wr, wb);
    deg4_kernel<<<(EE / 4 + 255) / 256, 256, 0, stream>>>((const int4*)src, (const int4*)dst,
                                                          pack, rank4);
    merge_kernel<<<(NN + 255) / 256, 256, 0, stream>>>(pack, indeg, ns, nd, base16);
    scan1_kernel<<<98, 1024, 0, stream>>>(indeg, partial, blocksum);
    scan23_kernel<<<(NN + 255) / 256, 256, 0, stream>>>(partial, blocksum, base16,
                                                        row_ofs, row_ofs2);
    cvt_kernel<<<(NN * 32 + 255) / 256, 256, 0, stream>>>((const float4*)feats, ns, fb4);
    fill4_kernel<<<(EE / 4 + 255) / 256, 256, 0, stream>>>((const int4*)src, (const int4*)dst,
                                                           rank4, row_ofs2, e_src);
    gather_kernel<<<NN / 16, 256, 0, stream>>>((const int4*)fb4, nd, row_ofs, e_src, y);
    gemm_kernel<<<NBLK, 256, 0, stream>>>((const float4*)feats, wb, b, br,
                                          y, part_sum, part_sq);
    colreduce_kernel<<<128, 256, 0, stream>>>(part_sum, part_sq, colsum, colsumsq);
    apply2_kernel<<<(NN * 32 + 255) / 256, 256, 0, stream>>>((float4*)y, colsum, colsumsq,
                                                             gamma, beta);
}

// Round 8
// 323.247 us; speedup vs baseline: 1.3753x; 1.3753x over previous
//
#include <hip/hip_runtime.h>

#define NN 100000
#define DD 128
#define EE 1600000
#define BN_EPS 1e-5f
#define NBLK 3125   // NN/32 gemm blocks
#define NCH 4       // node chunks
#define CH 25000    // nodes per chunk (NN = NCH*CH)
#define NEB 64      // edge blocks
#define EPB (EE / NEB)   // 25000 edges per block

using bf16x8 = __attribute__((ext_vector_type(8))) short;
using f32x4  = __attribute__((ext_vector_type(4))) float;

__device__ __forceinline__ unsigned short bf16r(float f) {
    unsigned u = __float_as_uint(f);
    u += 0x7FFF + ((u >> 16) & 1);   // round-to-nearest-even
    return (unsigned short)(u >> 16);
}
__device__ __forceinline__ float bf2f(unsigned short h) {
    return __uint_as_float((unsigned)h << 16);
}

// ---------------- LDS-histogram degree pass (NO global atomics) ----------------
// Block (c,j): scan edge range j, histogram src(outdeg)/dst(indeg) for nodes in
// chunk c into LDS (lo16=out, hi16=in). dst atomic return = rank within
// (node, eblock) -> lrank[e]. Flush counts to u16 tables outT/inT[NEB][NN].
// 100KB LDS -> 1 block/CU, 512 threads = 8 waves.
__global__ __launch_bounds__(512) void hist_kernel(
    const int4* __restrict__ src4, const int4* __restrict__ dst4,
    unsigned short* __restrict__ outT, unsigned short* __restrict__ inT,
    unsigned short* __restrict__ lrank) {
    __shared__ unsigned cnt[CH];
    const int j = blockIdx.x & (NEB - 1);
    const int c = blockIdx.x >> 6;
    const int clo = c * CH;
    const int t = threadIdx.x;
    for (int i = t; i < CH; i += 512) cnt[i] = 0;
    __syncthreads();
    const int base = j * (EPB / 4);
    for (int i = t; i < EPB / 4; i += 512) {
        int4 s = src4[base + i];
        int4 d = dst4[base + i];
        int e = j * EPB + i * 4;
        unsigned sx = (unsigned)(s.x - clo);
        unsigned sy = (unsigned)(s.y - clo);
        unsigned sz = (unsigned)(s.z - clo);
        unsigned sw = (unsigned)(s.w - clo);
        if (sx < CH) atomicAdd(&cnt[sx], 1u);
        if (sy < CH) atomicAdd(&cnt[sy], 1u);
        if (sz < CH) atomicAdd(&cnt[sz], 1u);
        if (sw < CH) atomicAdd(&cnt[sw], 1u);
        unsigned dx = (unsigned)(d.x - clo);
        unsigned dy = (unsigned)(d.y - clo);
        unsigned dz = (unsigned)(d.z - clo);
        unsigned dw = (unsigned)(d.w - clo);
        if (dx < CH) { unsigned o = atomicAdd(&cnt[dx], 0x10000u); lrank[e + 0] = (unsigned short)(o >> 16); }
        if (dy < CH) { unsigned o = atomicAdd(&cnt[dy], 0x10000u); lrank[e + 1] = (unsigned short)(o >> 16); }
        if (dz < CH) { unsigned o = atomicAdd(&cnt[dz], 0x10000u); lrank[e + 2] = (unsigned short)(o >> 16); }
        if (dw < CH) { unsigned o = atomicAdd(&cnt[dw], 0x10000u); lrank[e + 3] = (unsigned short)(o >> 16); }
    }
    __syncthreads();
    unsigned short* op = outT + (size_t)j * NN + clo;
    unsigned short* ip = inT + (size_t)j * NN + clo;
    for (int i = t; i < CH; i += 512) {
        unsigned v = cnt[i];
        op[i] = (unsigned short)(v & 0xFFFFu);
        ip[i] = (unsigned short)(v >> 16);
    }
}

// ---------------- per-node: outdeg sum -> ns; exclusive scan of inT over eblocks ----------------
// inT is rewritten in place: counts -> exclusive base per (node, eblock).
__global__ void degscan_kernel(const unsigned short* __restrict__ outT,
                               unsigned short* __restrict__ inT,
                               int* __restrict__ indeg, float* __restrict__ ns,
                               float* __restrict__ nd) {
    int n = blockIdx.x * blockDim.x + threadIdx.x;
    if (n < NN) {
        int run_in = 0, run_out = 0;
#pragma unroll 8
        for (int j = 0; j < NEB; ++j) {
            run_out += (int)outT[(size_t)j * NN + n];
            int ci = (int)inT[(size_t)j * NN + n];
            inT[(size_t)j * NN + n] = (unsigned short)run_in;
            run_in += ci;
        }
        indeg[n] = run_in;
        ns[n] = rsqrtf(fmaxf((float)run_out, 1.0f));
        nd[n] = rsqrtf(fmaxf((float)run_in, 1.0f));
    }
}

// ---------------- scan phase 1: per-block inclusive scan of indeg ----------------
__global__ __launch_bounds__(1024) void scan1_kernel(const int* __restrict__ indeg,
                                                     int* __restrict__ partial,
                                                     int* __restrict__ blocksum) {
    __shared__ int s[1024];
    int t = threadIdx.x;
    int idx = blockIdx.x * 1024 + t;
    int v = (idx < NN) ? indeg[idx] : 0;
    s[t] = v;
    __syncthreads();
    for (int off = 1; off < 1024; off <<= 1) {
        int x = (t >= off) ? s[t - off] : 0;
        __syncthreads();
        s[t] += x;
        __syncthreads();
    }
    if (idx < NN) partial[idx] = s[t] - v;  // exclusive within block
    if (t == 1023) blocksum[blockIdx.x] = s[t];
}

// ---------------- scan 2+3: row_ofs ----------------
__global__ void scan23_kernel(const int* __restrict__ partial, const int* __restrict__ blocksum,
                              int* __restrict__ row_ofs) {
    __shared__ int s[128];
    int t = threadIdx.x;
    if (t < 128) s[t] = (t < 98) ? blocksum[t] : 0;
    __syncthreads();
    for (int off = 1; off < 128; off <<= 1) {
        int x = (t < 128 && t >= off) ? s[t - off] : 0;
        __syncthreads();
        if (t < 128) s[t] += x;
        __syncthreads();
    }
    int i = blockIdx.x * blockDim.x + t;
    if (i < NN) {
        int bk = i >> 10;
        row_ofs[i] = partial[i] + s[bk] - blocksum[bk];
        if (i == 0) row_ofs[NN] = EE;
    }
}

// ---------------- CSR fill, atomic-free: slot = row_ofs[dst] + base[j][dst] + lrank ----------------
__global__ void fill4_kernel(const int4* __restrict__ src4, const int4* __restrict__ dst4,
                             const unsigned short* __restrict__ baseT,
                             const ushort4* __restrict__ lrank4,
                             const int* __restrict__ row_ofs, int* __restrict__ e_src) {
    int i = blockIdx.x * blockDim.x + threadIdx.x;
    if (i < EE / 4) {
        int4 s = src4[i];
        int4 d = dst4[i];
        ushort4 r = lrank4[i];
        int j = (i * 4) / EPB;                    // EPB%4==0 -> same j for all 4
        const unsigned short* bT = baseT + (size_t)j * NN;
        e_src[row_ofs[d.x] + (int)bT[d.x] + (int)r.x] = s.x;
        e_src[row_ofs[d.y] + (int)bT[d.y] + (int)r.y] = s.y;
        e_src[row_ofs[d.z] + (int)bT[d.z] + (int)r.z] = s.z;
        e_src[row_ofs[d.w] + (int)bT[d.w] + (int)r.w] = s.w;
    }
}

// ---------------- feats -> bf16 pre-scaled by ns ----------------
__global__ void cvt_kernel(const float4* __restrict__ feats4, const float* __restrict__ ns,
                           ushort4* __restrict__ fb4) {
    int i = blockIdx.x * blockDim.x + threadIdx.x;  // NN*32 = 3.2M
    if (i < NN * 32) {
        float s = ns[i >> 5];
        float4 v = feats4[i];
        ushort4 h;
        h.x = bf16r(v.x * s);
        h.y = bf16r(v.y * s);
        h.z = bf16r(v.z * s);
        h.w = bf16r(v.w * s);
        fb4[i] = h;
    }
}

// ---------------- weight pre-pack into MFMA B-fragment order, bf16 hi/lo ----------------
// B-frag for mfma_f32_16x16x32_bf16: lane l, elem i -> B[k = ks*32 + (l>>4)*8 + i][col = ct*16 + (l&15)]
__global__ void prepw_kernel(const float* __restrict__ W, const float* __restrict__ Wr,
                             unsigned short* __restrict__ wb) {
    int g = blockIdx.x >> 5;          // 0 = W, 1 = Wr
    int f = blockIdx.x & 31;          // ct*4 + ks
    int ct = f >> 2, ks = f & 3;
    int l = threadIdx.x;              // 0..63
    const float* G = g ? Wr : W;
    unsigned short* hi = wb + (((size_t)(g * 2 + 0) * 32 + f) * 64 + l) * 8;
    unsigned short* lo = wb + (((size_t)(g * 2 + 1) * 32 + f) * 64 + l) * 8;
    for (int i = 0; i < 8; ++i) {
        int k = ks * 32 + (l >> 4) * 8 + i;
        int col = ct * 16 + (l & 15);
        float w = G[k * 128 + col];
        unsigned uh = __float_as_uint(w) & 0xFFFF0000u;  // truncated hi part
        hi[i] = (unsigned short)(uh >> 16);
        lo[i] = bf16r(w - __uint_as_float(uh));          // residual -> lo
    }
}

// ---------------- gather-aggregate: latency-bound, no LDS, max occupancy ----------------
__device__ __forceinline__ void accum8(float* a, int4 u) {
    a[0] += __uint_as_float((unsigned)u.x << 16);
    a[1] += __uint_as_float((unsigned)u.x & 0xFFFF0000u);
    a[2] += __uint_as_float((unsigned)u.y << 16);
    a[3] += __uint_as_float((unsigned)u.y & 0xFFFF0000u);
    a[4] += __uint_as_float((unsigned)u.z << 16);
    a[5] += __uint_as_float((unsigned)u.z & 0xFFFF0000u);
    a[6] += __uint_as_float((unsigned)u.w << 16);
    a[7] += __uint_as_float((unsigned)u.w & 0xFFFF0000u);
}

__global__ __launch_bounds__(256, 6) void gather_kernel(
    const int4* __restrict__ fbi, const float* __restrict__ nd,
    const int* __restrict__ row_ofs, const int* __restrict__ e_src,
    float* __restrict__ y) {
    const int lane = threadIdx.x & 15;
    const int grp = threadIdx.x >> 4;                 // 0..15
    const int node = blockIdx.x * 16 + grp;           // 6250*16 = 100000 exact
    const int beg = row_ofs[node];
    const int end = row_ofs[node + 1];

    float a0[8] = {0.f, 0.f, 0.f, 0.f, 0.f, 0.f, 0.f, 0.f};
    float a1[8] = {0.f, 0.f, 0.f, 0.f, 0.f, 0.f, 0.f, 0.f};

    for (int e = beg; e < end; e += 16) {
        int cnt = end - e;
        if (cnt > 16) cnt = 16;
        int myidx = (lane < cnt) ? e_src[e + lane] : 0;
        int j = 0;
        for (; j + 3 < cnt; j += 4) {
            int s0 = __shfl(myidx, j, 16);
            int s1 = __shfl(myidx, j + 1, 16);
            int s2 = __shfl(myidx, j + 2, 16);
            int s3 = __shfl(myidx, j + 3, 16);
            int4 u0 = fbi[(size_t)s0 * 16 + lane];
            int4 u1 = fbi[(size_t)s1 * 16 + lane];
            int4 u2 = fbi[(size_t)s2 * 16 + lane];
            int4 u3 = fbi[(size_t)s3 * 16 + lane];
            accum8(a0, u0);
            accum8(a1, u1);
            accum8(a0, u2);
            accum8(a1, u3);
        }
        for (; j < cnt; ++j) {
            int s0 = __shfl(myidx, j, 16);
            int4 u0 = fbi[(size_t)s0 * 16 + lane];
            accum8(a0, u0);
        }
    }

    float snd = nd[node];
    float4 o0, o1;
    o0.x = (a0[0] + a1[0]) * snd;
    o0.y = (a0[1] + a1[1]) * snd;
    o0.z = (a0[2] + a1[2]) * snd;
    o0.w = (a0[3] + a1[3]) * snd;
    o1.x = (a0[4] + a1[4]) * snd;
    o1.y = (a0[5] + a1[5]) * snd;
    o1.z = (a0[6] + a1[6]) * snd;
    o1.w = (a0[7] + a1[7]) * snd;
    ((float4*)y)[(size_t)node * 32 + lane * 2] = o0;
    ((float4*)y)[(size_t)node * 32 + lane * 2 + 1] = o1;
}

// ---------------- dual MFMA GEMM + bias/relu/add + per-block BN partials ----------------
__device__ __forceinline__ void hilo4(float4 v, ushort4& h, ushort4& l) {
    unsigned u0 = __float_as_uint(v.x) & 0xFFFF0000u;
    unsigned u1 = __float_as_uint(v.y) & 0xFFFF0000u;
    unsigned u2 = __float_as_uint(v.z) & 0xFFFF0000u;
    unsigned u3 = __float_as_uint(v.w) & 0xFFFF0000u;
    h.x = (unsigned short)(u0 >> 16);
    h.y = (unsigned short)(u1 >> 16);
    h.z = (unsigned short)(u2 >> 16);
    h.w = (unsigned short)(u3 >> 16);
    l.x = bf16r(v.x - __uint_as_float(u0));
    l.y = bf16r(v.y - __uint_as_float(u1));
    l.z = bf16r(v.z - __uint_as_float(u2));
    l.w = bf16r(v.w - __uint_as_float(u3));
}

__global__ __launch_bounds__(256, 4) void gemm_kernel(
    const float4* __restrict__ feats4,
    const unsigned short* __restrict__ wb,
    const float* __restrict__ b, const float* __restrict__ br,
    float* y, float* __restrict__ part_sum, float* __restrict__ part_sq) {
    __shared__ unsigned short AsH[32 * 128];
    __shared__ unsigned short AsL[32 * 128];
    __shared__ unsigned short FsH[32 * 128];
    __shared__ unsigned short FsL[32 * 128];

    const int tid = threadIdx.x;
    const int block_row = blockIdx.x * 32;
    const float4* agg4 = (const float4*)y;   // NOT restrict: aliases the y store

    // ---- coalesced staging: agg (from y) + feats -> bf16 hi/lo, swizzled LDS ----
    for (int i = tid; i < 1024; i += 256) {
        int r = i >> 5;
        int c4 = i & 31;
        size_t g = (size_t)(block_row + r) * 32 + c4;
        float4 a = agg4[g];
        float4 f = feats4[g];
        int off = (r * 256 + ((c4 * 8) ^ ((r & 7) << 4))) >> 1;  // ushort index
        ushort4 h, l;
        hilo4(a, h, l);
        *(ushort4*)(&AsH[off]) = h;
        *(ushort4*)(&AsL[off]) = l;
        hilo4(f, h, l);
        *(ushort4*)(&FsH[off]) = h;
        *(ushort4*)(&FsL[off]) = l;
    }
    __syncthreads();

    // ---- MFMA phase: wave w covers all 32 rows x cols [w*32, w*32+31] ----
    const int w = tid >> 6;
    const int l = tid & 63;
    const int lr = l & 15;
    const int lh = l >> 4;
    const int ct0 = w * 2;
    const bf16x8* WB = (const bf16x8*)wb;

    const f32x4 fzero = {0.f, 0.f, 0.f, 0.f};
    f32x4 aC[2][2], aR[2][2];  // [row-frag][col-tile]
#pragma unroll
    for (int r = 0; r < 2; ++r)
#pragma unroll
        for (int c = 0; c < 2; ++c) { aC[r][c] = fzero; aR[r][c] = fzero; }

#pragma unroll 1
    for (int ks = 0; ks < 4; ++ks) {
        bf16x8 ah[2], al[2], fh[2], fl[2];
#pragma unroll
        for (int r = 0; r < 2; ++r) {
            int row = r * 16 + lr;
            int off = (row * 256 + ((ks * 64 + lh * 16) ^ ((row & 7) << 4))) >> 1;
            ah[r] = *(const bf16x8*)(&AsH[off]);
            al[r] = *(const bf16x8*)(&AsL[off]);
            fh[r] = *(const bf16x8*)(&FsH[off]);
            fl[r] = *(const bf16x8*)(&FsL[off]);
        }
#pragma unroll
        for (int c = 0; c < 2; ++c) {
            int fr = (ct0 + c) * 4 + ks;
            bf16x8 wh  = WB[(0 * 32 + fr) * 64 + l];
            bf16x8 wl  = WB[(1 * 32 + fr) * 64 + l];
            bf16x8 wrh = WB[(2 * 32 + fr) * 64 + l];
            bf16x8 wrl = WB[(3 * 32 + fr) * 64 + l];
#pragma unroll
            for (int r = 0; r < 2; ++r) {
                aC[r][c] = __builtin_amdgcn_mfma_f32_16x16x32_bf16(ah[r], wh, aC[r][c], 0, 0, 0);
                aC[r][c] = __builtin_amdgcn_mfma_f32_16x16x32_bf16(al[r], wh, aC[r][c], 0, 0, 0);
                aC[r][c] = __builtin_amdgcn_mfma_f32_16x16x32_bf16(ah[r], wl, aC[r][c], 0, 0, 0);
                aR[r][c] = __builtin_amdgcn_mfma_f32_16x16x32_bf16(fh[r], wrh, aR[r][c], 0, 0, 0);
                aR[r][c] = __builtin_amdgcn_mfma_f32_16x16x32_bf16(fl[r], wrh, aR[r][c], 0, 0, 0);
                aR[r][c] = __builtin_amdgcn_mfma_f32_16x16x32_bf16(fh[r], wrl, aR[r][c], 0, 0, 0);
            }
        }
    }

    // ---- epilogue: bias/relu/add, store, per-block BN partials (no atomics) ----
#pragma unroll
    for (int c = 0; c < 2; ++c) {
        int col = (ct0 + c) * 16 + lr;
        float bv = b[col], brv = br[col];
        float cs = 0.f, cq = 0.f;
#pragma unroll
        for (int r = 0; r < 2; ++r) {
#pragma unroll
            for (int i = 0; i < 4; ++i) {
                float o = fmaxf(aC[r][c][i] + bv, 0.f) + fmaxf(aR[r][c][i] + brv, 0.f);
                int grow = block_row + r * 16 + lh * 4 + i;
                y[(size_t)grow * 128 + col] = o;
                cs += o;
                cq += o * o;
            }
        }
        cs += __shfl_xor(cs, 16); cs += __shfl_xor(cs, 32);
        cq += __shfl_xor(cq, 16); cq += __shfl_xor(cq, 32);
        if (lh == 0) {
            part_sum[(size_t)blockIdx.x * 128 + col] = cs;
            part_sq[(size_t)blockIdx.x * 128 + col] = cq;
        }
    }
}

// ---------------- fold the 3125 per-block partials into colsum/colsumsq ----------------
__global__ __launch_bounds__(256) void colreduce_kernel(
    const float* __restrict__ part_sum, const float* __restrict__ part_sq,
    float* __restrict__ colsum, float* __restrict__ colsumsq) {
    int j = blockIdx.x;            // 0..127 (column)
    int t = threadIdx.x;           // 0..255
    float s = 0.f, q = 0.f;
    for (int bb = t; bb < NBLK; bb += 256) {
        s += part_sum[(size_t)bb * 128 + j];
        q += part_sq[(size_t)bb * 128 + j];
    }
#pragma unroll
    for (int off = 1; off < 64; off <<= 1) {
        s += __shfl_xor(s, off);
        q += __shfl_xor(q, off);
    }
    __shared__ float ss[4], qq[4];
    if ((t & 63) == 0) { ss[t >> 6] = s; qq[t >> 6] = q; }
    __syncthreads();
    if (t == 0) {
        colsum[j] = ss[0] + ss[1] + ss[2] + ss[3];
        colsumsq[j] = qq[0] + qq[1] + qq[2] + qq[3];
    }
}

// ---------------- BN stats + apply fused ----------------
__global__ void apply2_kernel(float4* __restrict__ y4,
                              const float* __restrict__ colsum, const float* __restrict__ colsumsq,
                              const float* __restrict__ gamma, const float* __restrict__ beta) {
    __shared__ float sc4[128], sh4[128];
    int t = threadIdx.x;
    if (t < 128) {
        const float inv_n = 1.0f / (float)NN;
        float mean = colsum[t] * inv_n;
        float var = colsumsq[t] * inv_n - mean * mean;
        float s = gamma[t] * rsqrtf(var + BN_EPS);
        sc4[t] = s;
        sh4[t] = beta[t] - mean * s;
    }
    __syncthreads();
    int i = blockIdx.x * 256 + t;
    if (i < NN * 32) {
        int c = (i & 31) * 4;
        float4 v = y4[i];
        v.x = v.x * sc4[c + 0] + sh4[c + 0];
        v.y = v.y * sc4[c + 1] + sh4[c + 1];
        v.z = v.z * sc4[c + 2] + sh4[c + 2];
        v.w = v.w * sc4[c + 3] + sh4[c + 3];
        y4[i] = v;
    }
}

extern "C" void kernel_launch(void* const* d_in, const int* in_sizes, int n_in,
                              void* d_out, int out_size, void* d_ws, size_t ws_size,
                              hipStream_t stream) {
    const float* feats = (const float*)d_in[0];
    const int* src = (const int*)d_in[1];
    const int* dst = (const int*)d_in[2];
    const float* W = (const float*)d_in[3];
    const float* b = (const float*)d_in[4];
    const float* Wr = (const float*)d_in[5];
    const float* br = (const float*)d_in[6];
    const float* gamma = (const float*)d_in[7];
    const float* beta = (const float*)d_in[8];
    float* y = (float*)d_out;

    // ---- workspace carve (aliased by lifetime) ----
    // Region A (28.8 MB): [outT 12.8 | inT 12.8 | lrank 3.2]
    //   outT/inT/lrank live hist..fill. fb4 (25.6MB, cvt..gather) aliases outT+inT.
    //   part_sum/part_sq (3.2MB, gemm..colreduce) alias lrank.
    char* ws = (char*)d_ws;
    unsigned short* outT = (unsigned short*)ws;               // [NEB][NN] u16
    unsigned short* inT = outT + (size_t)NEB * NN;            // [NEB][NN] u16 (-> baseT)
    unsigned short* lrank = inT + (size_t)NEB * NN;           // [EE] u16
    ushort4* fb4 = (ushort4*)ws;                              // NN*32 ushort4 = 25.6 MB
    float* part_sum = (float*)lrank;                          // NBLK*128 f32 = 1.6 MB
    float* part_sq = part_sum + (size_t)NBLK * 128;           // 1.6 MB
    char* wsB = ws + (size_t)2 * NEB * NN * 2 + (size_t)EE * 2;  // after region A
    float* ns = (float*)wsB;                                  // NN
    float* nd = ns + NN;                                      // NN
    int* row_ofs = (int*)(nd + NN);                           // NN+1
    int* indeg = row_ofs + NN + 1;                            // NN
    int* partial = indeg + NN;                                // NN
    int* blocksum = partial + NN;                             // 98 (pad 128)
    int* e_src = blocksum + 128;                              // EE
    float* colsum = (float*)(e_src + EE);                     // 128
    float* colsumsq = colsum + DD;                            // 128
    unsigned long long wbofs = (unsigned long long)((char*)(colsumsq + DD) - ws);
    wbofs = (wbofs + 255ull) & ~255ull;
    unsigned short* wb = (unsigned short*)(ws + wbofs);       // 128 KB

    prepw_kernel<<<64, 64, 0, stream>>>(W, Wr, wb);
    hist_kernel<<<NCH * NEB, 512, 0, stream>>>((const int4*)src, (const int4*)dst,
                                               outT, inT, lrank);
    degscan_kernel<<<(NN + 255) / 256, 256, 0, stream>>>(outT, inT, indeg, ns, nd);
    scan1_kernel<<<98, 1024, 0, stream>>>(indeg, partial, blocksum);
    scan23_kernel<<<(NN + 255) / 256, 256, 0, stream>>>(partial, blocksum, row_ofs);
    fill4_kernel<<<(EE / 4 + 255) / 256, 256, 0, stream>>>((const int4*)src, (const int4*)dst,
                                                           inT, (const ushort4*)lrank,
                                                           row_ofs, e_src);
    cvt_kernel<<<(NN * 32 + 255) / 256, 256, 0, stream>>>((const float4*)feats, ns, fb4);
    gather_kernel<<<NN / 16, 256, 0, stream>>>((const int4*)fb4, nd, row_ofs, e_src, y);
    gemm_kernel<<<NBLK, 256, 0, stream>>>((const float4*)feats, wb, b, br,
                                          y, part_sum, part_sq);
    colreduce_kernel<<<128, 256, 0, stream>>>(part_sum, part_sq, colsum, colsumsq);
    apply2_kernel<<<(NN * 32 + 255) / 256, 256, 0, stream>>>((float4*)y, colsum, colsumsq,
                                                             gamma, beta);
}